// Round 2
// baseline (351.347 us; speedup 1.0000x reference)
//
#include <hip/hip_runtime.h>

// ---------------------------------------------------------------------------
// Net_MP: two NNConv layers (2->32, 32->32) + Linear(32->1) on a graph.
// All f32. Per-edge weight matrices are generated on the fly (never stored).
// ---------------------------------------------------------------------------

// ---------------- conv1 edge kernel: 8 lanes per edge, 4 outputs/lane ------
__global__ __launch_bounds__(256) void edge1_kernel(
    const float* __restrict__ x,    // [N,2]
    const int*   __restrict__ ei,   // [2,E]
    const float* __restrict__ ea,   // [E,2]
    const float* __restrict__ w1,   // [2,16]
    const float* __restrict__ b1,   // [16]
    const float* __restrict__ w2,   // [16,64]
    const float* __restrict__ b2,   // [64]
    float* __restrict__ agg,        // [N,32] (atomic accum)
    int E)
{
    __shared__ float s_w2[16 * 64];
    __shared__ float s_b2[64];
    __shared__ float s_w1[32];
    __shared__ float s_b1[16];
    for (int t = threadIdx.x; t < 16 * 64; t += blockDim.x) s_w2[t] = w2[t];
    if (threadIdx.x < 64) s_b2[threadIdx.x] = b2[threadIdx.x];
    if (threadIdx.x < 32) s_w1[threadIdx.x] = w1[threadIdx.x];
    if (threadIdx.x < 16) s_b1[threadIdx.x] = b1[threadIdx.x];
    __syncthreads();

    int gid  = blockIdx.x * blockDim.x + threadIdx.x;
    int e    = gid >> 3;   // 8 lanes per edge
    int lane = gid & 7;    // output group: columns lane*4 .. lane*4+3
    if (e >= E) return;

    int src = ei[e];
    int dst = ei[E + e];
    float ea0 = ea[2 * e], ea1 = ea[2 * e + 1];

    float he[16];
#pragma unroll
    for (int k = 0; k < 16; ++k) {
        float v = fmaf(ea0, s_w1[k], fmaf(ea1, s_w1[16 + k], s_b1[k]));
        he[k] = v > 0.f ? v : 0.f;
    }

    float xs0 = x[2 * src], xs1 = x[2 * src + 1];

    const float4* w2v = reinterpret_cast<const float4*>(s_w2); // row = 16 float4
    const float4* b2v = reinterpret_cast<const float4*>(s_b2);
    float4 msg = make_float4(0.f, 0.f, 0.f, 0.f);
#pragma unroll
    for (int i = 0; i < 2; ++i) {
        float4 w = b2v[i * 8 + lane];
#pragma unroll
        for (int k = 0; k < 16; ++k) {
            float4 wv = w2v[k * 16 + i * 8 + lane];
            w.x = fmaf(he[k], wv.x, w.x);
            w.y = fmaf(he[k], wv.y, w.y);
            w.z = fmaf(he[k], wv.z, w.z);
            w.w = fmaf(he[k], wv.w, w.w);
        }
        float xs = i ? xs1 : xs0;
        msg.x = fmaf(xs, w.x, msg.x);
        msg.y = fmaf(xs, w.y, msg.y);
        msg.z = fmaf(xs, w.z, msg.z);
        msg.w = fmaf(xs, w.w, msg.w);
    }
    float* p = agg + (size_t)dst * 32 + lane * 4;
    atomicAdd(p + 0, msg.x);
    atomicAdd(p + 1, msg.y);
    atomicAdd(p + 2, msg.z);
    atomicAdd(p + 3, msg.w);
}

// ---------------- node update 1: h1 = relu(agg1 + x@root1 + bias1) ---------
__global__ __launch_bounds__(256) void node1_kernel(
    const float* __restrict__ x,     // [N,2]
    const float* __restrict__ agg,   // [N,32]
    const float* __restrict__ root,  // [2,32]
    const float* __restrict__ bias,  // [32]
    float* __restrict__ h1,          // [N,32]
    int N)
{
    int gid = blockIdx.x * blockDim.x + threadIdx.x;
    int n = gid >> 5, o = gid & 31;
    if (n >= N) return;
    float v = agg[(size_t)n * 32 + o]
            + x[2 * n] * root[o] + x[2 * n + 1] * root[32 + o] + bias[o];
    h1[(size_t)n * 32 + o] = v > 0.f ? v : 0.f;
}

// ---------------- conv2 edge kernel: 8 lanes/edge, 4 outputs/lane ----------
// nn2_w2 (16x1024, 64KB) staged in LDS; duplicate edges in a wave read the
// same LDS addresses -> broadcast, conflict-free.
__global__ __launch_bounds__(512) void edge2_kernel(
    const float* __restrict__ h1,   // [N,32]
    const int*   __restrict__ ei,   // [2,E]
    const float* __restrict__ ea,   // [E,2]
    const float* __restrict__ w1,   // [2,16]
    const float* __restrict__ b1,   // [16]
    const float* __restrict__ w2,   // [16,1024]
    const float* __restrict__ b2,   // [1024]
    float* __restrict__ agg,        // [N,32] (atomic accum)
    int E)
{
    __shared__ float s_w2[16 * 1024];  // 64 KB
    __shared__ float s_b2[1024];       // 4 KB
    __shared__ float s_w1[32];
    __shared__ float s_b1[16];
    for (int t = threadIdx.x; t < 16 * 1024 / 4; t += blockDim.x)
        reinterpret_cast<float4*>(s_w2)[t] = reinterpret_cast<const float4*>(w2)[t];
    for (int t = threadIdx.x; t < 1024 / 4; t += blockDim.x)
        reinterpret_cast<float4*>(s_b2)[t] = reinterpret_cast<const float4*>(b2)[t];
    if (threadIdx.x < 32) s_w1[threadIdx.x] = w1[threadIdx.x];
    if (threadIdx.x < 16) s_b1[threadIdx.x] = b1[threadIdx.x];
    __syncthreads();

    const float4* w2v = reinterpret_cast<const float4*>(s_w2); // row = 256 f4
    const float4* b2v = reinterpret_cast<const float4*>(s_b2);

    int lane  = threadIdx.x & 7;   // output group
    int eslot = threadIdx.x >> 3;  // 0..63 within block
    int tiles = (E + 63) >> 6;     // 64 edges per block-iteration

    for (int t = blockIdx.x; t < tiles; t += gridDim.x) {
        int e = t * 64 + eslot;
        if (e < E) {  // uniform within each 8-lane group
            int src = ei[e];
            int dst = ei[E + e];
            float ea0 = ea[2 * e], ea1 = ea[2 * e + 1];

            float he[16];
#pragma unroll
            for (int k = 0; k < 16; ++k) {
                float v = fmaf(ea0, s_w1[k], fmaf(ea1, s_w1[16 + k], s_b1[k]));
                he[k] = v > 0.f ? v : 0.f;
            }

            // this lane owns h_src[lane*4 .. lane*4+3]; the rest via shuffle
            float4 h4 = reinterpret_cast<const float4*>(h1 + (size_t)src * 32)[lane];
            float hreg[4] = {h4.x, h4.y, h4.z, h4.w};

            float4 msg = make_float4(0.f, 0.f, 0.f, 0.f);
#pragma unroll 2
            for (int io = 0; io < 8; ++io) {
#pragma unroll
                for (int j = 0; j < 4; ++j) {
                    int i = io * 4 + j;           // input channel
                    float hs = __shfl(hreg[j], io, 8);
                    float4 w = b2v[i * 8 + lane];
#pragma unroll
                    for (int k = 0; k < 16; ++k) {
                        float4 wv = w2v[k * 256 + i * 8 + lane];
                        w.x = fmaf(he[k], wv.x, w.x);
                        w.y = fmaf(he[k], wv.y, w.y);
                        w.z = fmaf(he[k], wv.z, w.z);
                        w.w = fmaf(he[k], wv.w, w.w);
                    }
                    msg.x = fmaf(hs, w.x, msg.x);
                    msg.y = fmaf(hs, w.y, msg.y);
                    msg.z = fmaf(hs, w.z, msg.z);
                    msg.w = fmaf(hs, w.w, msg.w);
                }
            }
            float* p = agg + (size_t)dst * 32 + lane * 4;
            atomicAdd(p + 0, msg.x);
            atomicAdd(p + 1, msg.y);
            atomicAdd(p + 2, msg.z);
            atomicAdd(p + 3, msg.w);
        }
    }
}

// ------- node update 2 + fc2: out = relu(agg2 + h1@root2 + b2) @ fc2_w + b -
__global__ __launch_bounds__(256) void node2_kernel(
    const float* __restrict__ h1,     // [N,32]
    const float* __restrict__ agg,    // [N,32]
    const float* __restrict__ root2,  // [32,32]
    const float* __restrict__ bias2,  // [32]
    const float* __restrict__ fc2w,   // [32,1]
    const float* __restrict__ fc2b,   // [1]
    float* __restrict__ out,          // [N]
    int N)
{
    __shared__ float s_r[1024];
    for (int t = threadIdx.x; t < 1024; t += blockDim.x) s_r[t] = root2[t];
    __syncthreads();

    int gid = blockIdx.x * blockDim.x + threadIdx.x;
    int n = gid >> 5, o = gid & 31;
    if (n >= N) return;

    float mine = h1[(size_t)n * 32 + o];
    float v = agg[(size_t)n * 32 + o] + bias2[o];
#pragma unroll
    for (int i = 0; i < 32; ++i) {
        float hi = __shfl(mine, i, 32);
        v = fmaf(hi, s_r[i * 32 + o], v);
    }
    v = v > 0.f ? v : 0.f;
    v *= fc2w[o];
#pragma unroll
    for (int off = 16; off; off >>= 1) v += __shfl_xor(v, off, 32);
    if (o == 0) out[n] = v + fc2b[0];
}

extern "C" void kernel_launch(void* const* d_in, const int* in_sizes, int n_in,
                              void* d_out, int out_size, void* d_ws, size_t ws_size,
                              hipStream_t stream) {
    const float* x      = (const float*)d_in[0];
    const int*   ei     = (const int*)  d_in[1];
    const float* ea     = (const float*)d_in[2];
    const float* nn1_w1 = (const float*)d_in[3];
    const float* nn1_b1 = (const float*)d_in[4];
    const float* nn1_w2 = (const float*)d_in[5];
    const float* nn1_b2 = (const float*)d_in[6];
    const float* root1  = (const float*)d_in[7];
    const float* bias1  = (const float*)d_in[8];
    const float* nn2_w1 = (const float*)d_in[9];
    const float* nn2_b1 = (const float*)d_in[10];
    const float* nn2_w2 = (const float*)d_in[11];
    const float* nn2_b2 = (const float*)d_in[12];
    const float* root2  = (const float*)d_in[13];
    const float* bias2  = (const float*)d_in[14];
    const float* fc2w   = (const float*)d_in[15];
    const float* fc2b   = (const float*)d_in[16];

    const int N = in_sizes[0] / 2;   // x is [N,2]
    const int E = in_sizes[2] / 2;   // edge_attr is [E,2]

    float* agg1 = (float*)d_ws;                    // [N,32]
    float* agg2 = agg1 + (size_t)N * 32;           // [N,32]
    float* h1   = agg2 + (size_t)N * 32;           // [N,32]

    // zero both aggregation buffers (ws is poisoned before every call)
    hipMemsetAsync(d_ws, 0, (size_t)N * 64 * sizeof(float), stream);

    edge1_kernel<<<(E * 8 + 255) / 256, 256, 0, stream>>>(
        x, ei, ea, nn1_w1, nn1_b1, nn1_w2, nn1_b2, agg1, E);

    node1_kernel<<<(N * 32 + 255) / 256, 256, 0, stream>>>(
        x, agg1, root1, bias1, h1, N);

    edge2_kernel<<<512, 512, 0, stream>>>(
        h1, ei, ea, nn2_w1, nn2_b1, nn2_w2, nn2_b2, agg2, E);

    node2_kernel<<<(N * 32 + 255) / 256, 256, 0, stream>>>(
        h1, agg2, root2, bias2, fc2w, fc2b, (float*)d_out, N);
}

// Round 5
// 193.813 us; speedup vs baseline: 1.8128x; 1.8128x over previous
//
#include <hip/hip_runtime.h>

// ---------------------------------------------------------------------------
// Net_MP: two NNConv layers (2->32, 32->32) + Linear(32->1) on a graph.
// Conv edge phases recast as bf16 MFMA GEMMs:
//   msg[e,o] = sum_{k,i} (he[e,k]*h_src[e,i]) * w2[k, i*32+o]  (+ bias rows)
// => per-edge outer-product vector u[e] (K=16*IN+IN) times shared WrT[K,32].
// ---------------------------------------------------------------------------

typedef __attribute__((ext_vector_type(8))) short short8;   // 8 bf16 (4 VGPR)
typedef __attribute__((ext_vector_type(4))) float f32x4;

__device__ inline unsigned short f2bf(float f) {
    unsigned x = __float_as_uint(f);
    unsigned r = (x + 0x7fffu + ((x >> 16) & 1u)) >> 16;   // round-nearest-even
    return (unsigned short)r;
}
__device__ inline unsigned long long pack4bf(float a, float b, float c, float d) {
    return (unsigned long long)f2bf(a) | ((unsigned long long)f2bf(b) << 16)
         | ((unsigned long long)f2bf(c) << 32) | ((unsigned long long)f2bf(d) << 48);
}

// ======================= conv2 edge phase (K = 544) ========================
// u[e][kk]: kk = k*32+i (k<16), kk = 512+i bias rows. Row stride 1152 B.
// A-frag: lane l reads u[row=l&15-ish][16B slot], XOR-swizzled by row&7.
__global__ __launch_bounds__(256, 2) void edge2_mfma(
    const float* __restrict__ h1,   // [N,32]
    const int*   __restrict__ ei,   // [2,E]
    const float* __restrict__ ea,   // [E,2]
    const float* __restrict__ w1,   // [2,16]
    const float* __restrict__ b1,   // [16]
    const float* __restrict__ w2,   // [16,1024]
    const float* __restrict__ b2,   // [1024]
    float* __restrict__ agg,        // [N,32] atomic accum
    int E)
{
    __shared__ short8 u_buf[32 * 1152 / 16];    // 36864 B, 32 edge rows
    __shared__ short8 wrt_buf[32 * 1152 / 16];  // 36864 B, 32 out rows
    __shared__ int s_dst[32];
    char* u_lds = (char*)u_buf;
    char* wrt   = (char*)wrt_buf;

    const int tid = threadIdx.x;

    // ---- build WrT[o][kk] (bf16), one-time ----
    for (int idx = tid; idx < 32 * 544; idx += 256) {
        int o  = idx / 544;
        int kk = idx - o * 544;
        float v = (kk < 512) ? w2[(kk >> 5) * 1024 + (kk & 31) * 32 + o]
                             : b2[(kk - 512) * 32 + o];
        *(unsigned short*)(wrt + o * 1152 + kk * 2) = f2bf(v);
    }
    __syncthreads();

    // ---- per-wave constants ----
    const int lane = tid & 63;
    const int w    = tid >> 6;     // 0..3
    const int m    = w & 1;        // edge subtile (16 edges)
    const int nh   = w >> 1;       // output half (16 outs)
    const int g16  = (lane >> 4) << 4;            // k-group byte offset
    const int oo   = nh * 16 + (lane & 15);       // my output column

    // B fragments (17 K-steps) pinned in registers
    const char* brow = wrt + (size_t)oo * 1152;
    short8 bfrag[17];
#pragma unroll
    for (int t = 0; t < 17; ++t)
        bfrag[t] = *(const short8*)(brow + t * 64 + g16);

    // edge-MLP weights (uniform -> scalar regs)
    float w1r0[16], w1r1[16], b1r[16];
#pragma unroll
    for (int k = 0; k < 16; ++k) {
        w1r0[k] = w1[k]; w1r1[k] = w1[16 + k]; b1r[k] = b1[k];
    }

    const int e_loc = tid >> 3, sub = tid & 7;
    const int arow_idx = m * 16 + (lane & 15);
    const char* arow = u_lds + (size_t)arow_idx * 1152;
    const unsigned axor = (unsigned)((arow_idx & 7) << 4);
    char* srow = u_lds + (size_t)e_loc * 1152;
    const unsigned sxor = (unsigned)((e_loc & 7) << 4);

    const int tiles = (E + 31) >> 5;
    for (int t0 = blockIdx.x; t0 < tiles; t0 += gridDim.x) {
        // ---- construct u for 32 edges (8 threads/edge) ----
        int e = t0 * 32 + e_loc;
        bool valid = e < E;
        int ec = valid ? e : 0;
        int src = ei[ec];
        if (sub == 0) s_dst[e_loc] = ei[E + ec];
        float ea0 = ea[2 * ec], ea1 = ea[2 * ec + 1];
        float4 h4 = *(const float4*)(h1 + (size_t)src * 32 + sub * 4);
        if (!valid) h4 = make_float4(0.f, 0.f, 0.f, 0.f);

        float he[16];
#pragma unroll
        for (int k = 0; k < 16; ++k) {
            float v = fmaf(ea0, w1r0[k], fmaf(ea1, w1r1[k], b1r[k]));
            he[k] = v > 0.f ? v : 0.f;
        }
#pragma unroll
        for (int k = 0; k < 16; ++k) {
            *(unsigned long long*)(srow + (((unsigned)(k * 64 + sub * 8)) ^ sxor)) =
                pack4bf(he[k] * h4.x, he[k] * h4.y, he[k] * h4.z, he[k] * h4.w);
        }
        // bias rows: u[512+i] = h_src[i]
        *(unsigned long long*)(srow + (((unsigned)(1024 + sub * 8)) ^ sxor)) =
            pack4bf(h4.x, h4.y, h4.z, h4.w);
        __syncthreads();

        // ---- MFMA: [16 edges x 544] @ [544 x 16 outs] ----
        f32x4 acc = {0.f, 0.f, 0.f, 0.f};
#pragma unroll
        for (int t = 0; t < 17; ++t) {
            short8 a = *(const short8*)(arow + (((unsigned)(t * 64 + g16)) ^ axor));
            acc = __builtin_amdgcn_mfma_f32_16x16x32_bf16(a, bfrag[t], acc, 0, 0, 0);
        }

        // ---- scatter: D row=(lane>>4)*4+reg (edge), col=lane&15 (out) ----
#pragma unroll
        for (int j = 0; j < 4; ++j) {
            int r  = ((lane >> 4) << 2) + j;
            int eg = t0 * 32 + m * 16 + r;
            if (eg < E) {
                int d = s_dst[m * 16 + r];
                atomicAdd(agg + (size_t)d * 32 + oo, acc[j]);
            }
        }
        __syncthreads();   // protect u_lds / s_dst before next tile
    }
}

// ======================= conv1 edge phase (K = 64) =========================
// u[e][kk]: kk = k*2+i (k<16), kk = 32+i bias, 34..63 zero. Row stride 128 B.
__global__ __launch_bounds__(256, 2) void edge1_mfma(
    const float* __restrict__ x,    // [N,2]
    const int*   __restrict__ ei,
    const float* __restrict__ ea,
    const float* __restrict__ w1,   // [2,16]
    const float* __restrict__ b1,   // [16]
    const float* __restrict__ w2,   // [16,64]
    const float* __restrict__ b2,   // [64]
    float* __restrict__ agg,        // [N,32]
    int E)
{
    __shared__ short8 u_buf[32 * 128 / 16];     // 4096 B
    __shared__ short8 wrt_buf[32 * 128 / 16];   // 4096 B
    __shared__ int s_dst[32];
    char* u_lds = (char*)u_buf;
    char* wrt   = (char*)wrt_buf;

    const int tid = threadIdx.x;

    for (int idx = tid; idx < 32 * 64; idx += 256) {
        int o = idx >> 6, kk = idx & 63;
        float v = 0.f;
        if (kk < 32)      v = w2[(kk >> 1) * 64 + (kk & 1) * 32 + o];
        else if (kk < 34) v = b2[(kk - 32) * 32 + o];
        *(unsigned short*)(wrt + o * 128 + kk * 2) = f2bf(v);
    }
    __syncthreads();

    const int lane = tid & 63;
    const int w    = tid >> 6;
    const int m    = w & 1;
    const int nh   = w >> 1;
    const int g16  = (lane >> 4) << 4;
    const int oo   = nh * 16 + (lane & 15);

    const char* brow = wrt + (size_t)oo * 128;
    short8 bfrag[2];
#pragma unroll
    for (int t = 0; t < 2; ++t)
        bfrag[t] = *(const short8*)(brow + t * 64 + g16);

    float w1r0[16], w1r1[16], b1r[16];
#pragma unroll
    for (int k = 0; k < 16; ++k) {
        w1r0[k] = w1[k]; w1r1[k] = w1[16 + k]; b1r[k] = b1[k];
    }

    const int e_loc = tid >> 3, sub = tid & 7;
    const int arow_idx = m * 16 + (lane & 15);
    const char* arow = u_lds + (size_t)arow_idx * 128;
    const unsigned axor = (unsigned)((arow_idx & 7) << 4);
    char* srow = u_lds + (size_t)e_loc * 128;
    const unsigned sxor = (unsigned)((e_loc & 7) << 4);

    const int tiles = (E + 31) >> 5;
    for (int t0 = blockIdx.x; t0 < tiles; t0 += gridDim.x) {
        int e = t0 * 32 + e_loc;
        bool valid = e < E;
        int ec = valid ? e : 0;
        int src = ei[ec];
        if (sub == 0) s_dst[e_loc] = ei[E + ec];
        float ea0 = ea[2 * ec], ea1 = ea[2 * ec + 1];
        float x0 = x[2 * src], x1 = x[2 * src + 1];
        if (!valid) { x0 = 0.f; x1 = 0.f; }

        float he[16];
#pragma unroll
        for (int k = 0; k < 16; ++k) {
            float v = fmaf(ea0, w1r0[k], fmaf(ea1, w1r1[k], b1r[k]));
            he[k] = v > 0.f ? v : 0.f;
        }
        // thread writes kk = sub*8 .. sub*8+7 (16 B, two b64 stores)
        float v8[8];
#pragma unroll
        for (int jj = 0; jj < 8; ++jj) {
            int kk = sub * 8 + jj;
            float v = 0.f;
            if (kk < 32)       v = he[kk >> 1] * ((kk & 1) ? x1 : x0);
            else if (kk == 32) v = x0;
            else if (kk == 33) v = x1;
            v8[jj] = v;
        }
        *(unsigned long long*)(srow + (((unsigned)(sub * 16)) ^ sxor)) =
            pack4bf(v8[0], v8[1], v8[2], v8[3]);
        *(unsigned long long*)(srow + (((unsigned)(sub * 16 + 8)) ^ sxor)) =
            pack4bf(v8[4], v8[5], v8[6], v8[7]);
        __syncthreads();

        f32x4 acc = {0.f, 0.f, 0.f, 0.f};
#pragma unroll
        for (int t = 0; t < 2; ++t) {
            short8 a = *(const short8*)(arow + (((unsigned)(t * 64 + g16)) ^ axor));
            acc = __builtin_amdgcn_mfma_f32_16x16x32_bf16(a, bfrag[t], acc, 0, 0, 0);
        }

#pragma unroll
        for (int j = 0; j < 4; ++j) {
            int r  = ((lane >> 4) << 2) + j;
            int eg = t0 * 32 + m * 16 + r;
            if (eg < E) {
                int d = s_dst[m * 16 + r];
                atomicAdd(agg + (size_t)d * 32 + oo, acc[j]);
            }
        }
        __syncthreads();
    }
}

// ---------------- node update 1: h1 = relu(agg1 + x@root1 + bias1) ---------
__global__ __launch_bounds__(256) void node1_kernel(
    const float* __restrict__ x, const float* __restrict__ agg,
    const float* __restrict__ root, const float* __restrict__ bias,
    float* __restrict__ h1, int N)
{
    int gid = blockIdx.x * blockDim.x + threadIdx.x;
    int n = gid >> 5, o = gid & 31;
    if (n >= N) return;
    float v = agg[(size_t)n * 32 + o]
            + x[2 * n] * root[o] + x[2 * n + 1] * root[32 + o] + bias[o];
    h1[(size_t)n * 32 + o] = v > 0.f ? v : 0.f;
}

// ------- node update 2 + fc2: out = relu(agg2 + h1@root2 + b2) @ fc2_w + b -
__global__ __launch_bounds__(256) void node2_kernel(
    const float* __restrict__ h1, const float* __restrict__ agg,
    const float* __restrict__ root2, const float* __restrict__ bias2,
    const float* __restrict__ fc2w, const float* __restrict__ fc2b,
    float* __restrict__ out, int N)
{
    __shared__ float s_r[1024];
    for (int t = threadIdx.x; t < 1024; t += blockDim.x) s_r[t] = root2[t];
    __syncthreads();

    int gid = blockIdx.x * blockDim.x + threadIdx.x;
    int n = gid >> 5, o = gid & 31;
    if (n >= N) return;

    float mine = h1[(size_t)n * 32 + o];
    float v = agg[(size_t)n * 32 + o] + bias2[o];
#pragma unroll
    for (int i = 0; i < 32; ++i) {
        float hi = __shfl(mine, i, 32);
        v = fmaf(hi, s_r[i * 32 + o], v);
    }
    v = v > 0.f ? v : 0.f;
    v *= fc2w[o];
#pragma unroll
    for (int off = 16; off; off >>= 1) v += __shfl_xor(v, off, 32);
    if (o == 0) out[n] = v + fc2b[0];
}

extern "C" void kernel_launch(void* const* d_in, const int* in_sizes, int n_in,
                              void* d_out, int out_size, void* d_ws, size_t ws_size,
                              hipStream_t stream) {
    const float* x      = (const float*)d_in[0];
    const int*   ei     = (const int*)  d_in[1];
    const float* ea     = (const float*)d_in[2];
    const float* nn1_w1 = (const float*)d_in[3];
    const float* nn1_b1 = (const float*)d_in[4];
    const float* nn1_w2 = (const float*)d_in[5];
    const float* nn1_b2 = (const float*)d_in[6];
    const float* root1  = (const float*)d_in[7];
    const float* bias1  = (const float*)d_in[8];
    const float* nn2_w1 = (const float*)d_in[9];
    const float* nn2_b1 = (const float*)d_in[10];
    const float* nn2_w2 = (const float*)d_in[11];
    const float* nn2_b2 = (const float*)d_in[12];
    const float* root2  = (const float*)d_in[13];
    const float* bias2  = (const float*)d_in[14];
    const float* fc2w   = (const float*)d_in[15];
    const float* fc2b   = (const float*)d_in[16];

    const int N = in_sizes[0] / 2;
    const int E = in_sizes[2] / 2;

    float* agg1 = (float*)d_ws;
    float* agg2 = agg1 + (size_t)N * 32;
    float* h1   = agg2 + (size_t)N * 32;

    hipMemsetAsync(d_ws, 0, (size_t)N * 64 * sizeof(float), stream);

    edge1_mfma<<<1024, 256, 0, stream>>>(
        x, ei, ea, nn1_w1, nn1_b1, nn1_w2, nn1_b2, agg1, E);

    node1_kernel<<<(N * 32 + 255) / 256, 256, 0, stream>>>(
        x, agg1, root1, bias1, h1, N);

    edge2_mfma<<<512, 256, 0, stream>>>(
        h1, ei, ea, nn2_w1, nn2_b1, nn2_w2, nn2_b2, agg2, E);

    node2_kernel<<<(N * 32 + 255) / 256, 256, 0, stream>>>(
        h1, agg2, root2, bias2, fc2w, fc2b, (float*)d_out, N);
}

// Round 6
// 169.896 us; speedup vs baseline: 2.0680x; 1.1408x over previous
//
#include <hip/hip_runtime.h>
#include <hip/hip_bf16.h>

// ---------------------------------------------------------------------------
// Net_MP: two NNConv layers (2->32, 32->32) + Linear(32->1) on a graph.
// Edge phases: per-edge outer-product u[e] (K = 16*IN + IN) contracted with a
// shared WrT[K,32] via bf16 MFMA. A-fragments are built DIRECTLY in registers
// (no LDS, no barriers): for mfma_16x16x32, lane l (row=l&15, g=l>>4) at
// K-step t needs u[kk = t*32 + g*8 + j] = he[t] * hsrc[g*8+j]  (kk = k*32+i).
// B-fragments (per output column oo) are loaded once per wave from global.
// ---------------------------------------------------------------------------

typedef __attribute__((ext_vector_type(8))) short short8;   // 8 bf16
typedef __attribute__((ext_vector_type(4))) float f32x4;

union frag_u { short8 s; unsigned u[4]; };

__device__ inline unsigned cvt_pk2(float lo, float hi) {
    union { __hip_bfloat162 h; unsigned u; } c;
    c.h = __float22bfloat162_rn(make_float2(lo, hi));   // v_cvt_pk_bf16_f32
    return c.u;
}

// ======================= conv2 edge phase (K = 544) ========================
__global__ __launch_bounds__(256, 4) void edge2_mfma(
    const float* __restrict__ h1,   // [N,32]
    const int*   __restrict__ ei,   // [2,E]
    const float* __restrict__ ea,   // [E,2]
    const float* __restrict__ w1,   // [2,16]
    const float* __restrict__ b1,   // [16]
    const float* __restrict__ w2,   // [16,1024] = [16][32in][32out]
    const float* __restrict__ b2,   // [1024] = [32in][32out]
    float* __restrict__ agg,        // [N,32] atomic accum
    int E)
{
    const int tid  = threadIdx.x;
    const int lane = tid & 63;
    const int wv   = tid >> 6;          // 0..3
    const int nh   = wv & 1;            // output half (16 cols)
    const int gsel = wv >> 1;           // edge-group within pair
    const int r16  = lane & 15;
    const int g    = lane >> 4;         // k-slice / D row-quad
    const int oo   = nh * 16 + r16;     // my output column
    const int g8   = g * 8;

    // ---- one-time: B fragments from global (w2 is L2-resident) ----
    short8 bfrag[17];
#pragma unroll
    for (int t = 0; t < 16; ++t) {
        frag_u f;
#pragma unroll
        for (int wd = 0; wd < 4; ++wd) {
            int i0 = g8 + 2 * wd;
            f.u[wd] = cvt_pk2(w2[t * 1024 + i0 * 32 + oo],
                              w2[t * 1024 + (i0 + 1) * 32 + oo]);
        }
        bfrag[t] = f.s;
    }
    {   // bias rows: kk = 512 + i  ->  b2[i*32 + oo]
        frag_u f;
#pragma unroll
        for (int wd = 0; wd < 4; ++wd) {
            int i0 = g8 + 2 * wd;
            f.u[wd] = cvt_pk2(b2[i0 * 32 + oo], b2[(i0 + 1) * 32 + oo]);
        }
        bfrag[16] = f.s;
    }

    // ---- edge-MLP weights (uniform) ----
    float w1r0[16], w1r1[16], b1r[16];
#pragma unroll
    for (int k = 0; k < 16; ++k) {
        w1r0[k] = w1[k]; w1r1[k] = w1[16 + k]; b1r[k] = b1[k];
    }

    const int pairs = (E + 31) >> 5;    // 32 edges per block-iter (2 groups)
    for (int p = blockIdx.x; p < pairs; p += gridDim.x) {
        const int base = p * 32 + gsel * 16;
        const int edge = base + r16;
        const bool ev = edge < E;
        const int ec = ev ? edge : 0;

        int    src = ei[ec];
        float2 eav = *(const float2*)(ea + 2 * (size_t)ec);
        float4 hA  = *(const float4*)(h1 + (size_t)src * 32 + g8);
        float4 hB  = *(const float4*)(h1 + (size_t)src * 32 + g8 + 4);
        if (!ev) { hA = make_float4(0.f,0.f,0.f,0.f); hB = make_float4(0.f,0.f,0.f,0.f); }

        float he[16];
#pragma unroll
        for (int k = 0; k < 16; ++k) {
            float v = fmaf(eav.x, w1r0[k], fmaf(eav.y, w1r1[k], b1r[k]));
            he[k] = v > 0.f ? v : 0.f;
        }

        f32x4 acc = {0.f, 0.f, 0.f, 0.f};
#pragma unroll
        for (int t = 0; t < 16; ++t) {
            frag_u a;
            a.u[0] = cvt_pk2(he[t] * hA.x, he[t] * hA.y);
            a.u[1] = cvt_pk2(he[t] * hA.z, he[t] * hA.w);
            a.u[2] = cvt_pk2(he[t] * hB.x, he[t] * hB.y);
            a.u[3] = cvt_pk2(he[t] * hB.z, he[t] * hB.w);
            acc = __builtin_amdgcn_mfma_f32_16x16x32_bf16(a.s, bfrag[t], acc, 0, 0, 0);
        }
        {   // bias rows: u[512+i] = hsrc[i]
            frag_u a;
            a.u[0] = cvt_pk2(hA.x, hA.y);
            a.u[1] = cvt_pk2(hA.z, hA.w);
            a.u[2] = cvt_pk2(hB.x, hB.y);
            a.u[3] = cvt_pk2(hB.z, hB.w);
            acc = __builtin_amdgcn_mfma_f32_16x16x32_bf16(a.s, bfrag[16], acc, 0, 0, 0);
        }

        // ---- scatter: D row r = g*4+j -> edge base+g*4+j, col = oo ----
        float* ap = agg + oo;
        if (base + g * 4 + 3 < E) {
            int4 d4 = *(const int4*)(ei + (size_t)E + base + g * 4);
            atomicAdd(ap + (size_t)d4.x * 32, acc[0]);
            atomicAdd(ap + (size_t)d4.y * 32, acc[1]);
            atomicAdd(ap + (size_t)d4.z * 32, acc[2]);
            atomicAdd(ap + (size_t)d4.w * 32, acc[3]);
        } else {
#pragma unroll
            for (int j = 0; j < 4; ++j) {
                int eg = base + g * 4 + j;
                if (eg < E) atomicAdd(ap + (size_t)ei[E + eg] * 32, acc[j]);
            }
        }
    }
}

// ======================= conv1 edge phase (K = 64) =========================
// kk = k*2+i (k<16), kk = 32+i bias, rest zero.
// Lane l at t=0 needs he[g*4 + (j>>1)] * x[j&1]; t=1 only g==0,j<2 nonzero.
__global__ __launch_bounds__(256, 4) void edge1_mfma(
    const float* __restrict__ x,    // [N,2]
    const int*   __restrict__ ei,
    const float* __restrict__ ea,
    const float* __restrict__ w1,   // [2,16]
    const float* __restrict__ b1,   // [16]
    const float* __restrict__ w2,   // [16,64] = [16][2][32]
    const float* __restrict__ b2,   // [64] = [2][32]
    float* __restrict__ agg,        // [N,32]
    int E)
{
    const int tid  = threadIdx.x;
    const int lane = tid & 63;
    const int wv   = tid >> 6;
    const int nh   = wv & 1;
    const int gsel = wv >> 1;
    const int r16  = lane & 15;
    const int g    = lane >> 4;
    const int oo   = nh * 16 + r16;
    const int g8   = g * 8;

    // B fragments
    short8 bf0, bf1;
    {
        frag_u f;
#pragma unroll
        for (int wd = 0; wd < 4; ++wd) {
            int kk0 = g8 + 2 * wd, kk1 = kk0 + 1;
            f.u[wd] = cvt_pk2(w2[(kk0 >> 1) * 64 + (kk0 & 1) * 32 + oo],
                              w2[(kk1 >> 1) * 64 + (kk1 & 1) * 32 + oo]);
        }
        bf0 = f.s;
        f.u[0] = (g == 0) ? cvt_pk2(b2[oo], b2[32 + oo]) : 0u;
        f.u[1] = 0u; f.u[2] = 0u; f.u[3] = 0u;
        bf1 = f.s;
    }

    const float4 w1a = *(const float4*)(w1 + g * 4);        // w1[0][g4..]
    const float4 w1b = *(const float4*)(w1 + 16 + g * 4);   // w1[1][g4..]
    const float4 b1v = *(const float4*)(b1 + g * 4);

    const int pairs = (E + 31) >> 5;
    for (int p = blockIdx.x; p < pairs; p += gridDim.x) {
        const int base = p * 32 + gsel * 16;
        const int edge = base + r16;
        const bool ev = edge < E;
        const int ec = ev ? edge : 0;

        int    src = ei[ec];
        float2 eav = *(const float2*)(ea + 2 * (size_t)ec);
        float2 xv  = *(const float2*)(x + 2 * (size_t)src);
        if (!ev) xv = make_float2(0.f, 0.f);

        float he0 = fmaf(eav.x, w1a.x, fmaf(eav.y, w1b.x, b1v.x)); he0 = he0 > 0.f ? he0 : 0.f;
        float he1 = fmaf(eav.x, w1a.y, fmaf(eav.y, w1b.y, b1v.y)); he1 = he1 > 0.f ? he1 : 0.f;
        float he2 = fmaf(eav.x, w1a.z, fmaf(eav.y, w1b.z, b1v.z)); he2 = he2 > 0.f ? he2 : 0.f;
        float he3 = fmaf(eav.x, w1a.w, fmaf(eav.y, w1b.w, b1v.w)); he3 = he3 > 0.f ? he3 : 0.f;

        frag_u a;
        a.u[0] = cvt_pk2(he0 * xv.x, he0 * xv.y);
        a.u[1] = cvt_pk2(he1 * xv.x, he1 * xv.y);
        a.u[2] = cvt_pk2(he2 * xv.x, he2 * xv.y);
        a.u[3] = cvt_pk2(he3 * xv.x, he3 * xv.y);
        f32x4 acc = {0.f, 0.f, 0.f, 0.f};
        acc = __builtin_amdgcn_mfma_f32_16x16x32_bf16(a.s, bf0, acc, 0, 0, 0);

        a.u[0] = (g == 0) ? cvt_pk2(xv.x, xv.y) : 0u;
        a.u[1] = 0u; a.u[2] = 0u; a.u[3] = 0u;
        acc = __builtin_amdgcn_mfma_f32_16x16x32_bf16(a.s, bf1, acc, 0, 0, 0);

        float* ap = agg + oo;
        if (base + g * 4 + 3 < E) {
            int4 d4 = *(const int4*)(ei + (size_t)E + base + g * 4);
            atomicAdd(ap + (size_t)d4.x * 32, acc[0]);
            atomicAdd(ap + (size_t)d4.y * 32, acc[1]);
            atomicAdd(ap + (size_t)d4.z * 32, acc[2]);
            atomicAdd(ap + (size_t)d4.w * 32, acc[3]);
        } else {
#pragma unroll
            for (int j = 0; j < 4; ++j) {
                int eg = base + g * 4 + j;
                if (eg < E) atomicAdd(ap + (size_t)ei[E + eg] * 32, acc[j]);
            }
        }
    }
}

// ---------------- node update 1: h1 = relu(agg1 + x@root1 + bias1) ---------
__global__ __launch_bounds__(256) void node1_kernel(
    const float* __restrict__ x, const float* __restrict__ agg,
    const float* __restrict__ root, const float* __restrict__ bias,
    float* __restrict__ h1, int N)
{
    int gid = blockIdx.x * blockDim.x + threadIdx.x;
    int n = gid >> 5, o = gid & 31;
    if (n >= N) return;
    float v = agg[(size_t)n * 32 + o]
            + x[2 * n] * root[o] + x[2 * n + 1] * root[32 + o] + bias[o];
    h1[(size_t)n * 32 + o] = v > 0.f ? v : 0.f;
}

// ------- node update 2 + fc2: out = relu(agg2 + h1@root2 + b2) @ fc2_w + b -
__global__ __launch_bounds__(256) void node2_kernel(
    const float* __restrict__ h1, const float* __restrict__ agg,
    const float* __restrict__ root2, const float* __restrict__ bias2,
    const float* __restrict__ fc2w, const float* __restrict__ fc2b,
    float* __restrict__ out, int N)
{
    __shared__ float s_r[1024];
    for (int t = threadIdx.x; t < 1024; t += blockDim.x) s_r[t] = root2[t];
    __syncthreads();

    int gid = blockIdx.x * blockDim.x + threadIdx.x;
    int n = gid >> 5, o = gid & 31;
    if (n >= N) return;

    float mine = h1[(size_t)n * 32 + o];
    float v = agg[(size_t)n * 32 + o] + bias2[o];
#pragma unroll
    for (int i = 0; i < 32; ++i) {
        float hi = __shfl(mine, i, 32);
        v = fmaf(hi, s_r[i * 32 + o], v);
    }
    v = v > 0.f ? v : 0.f;
    v *= fc2w[o];
#pragma unroll
    for (int off = 16; off; off >>= 1) v += __shfl_xor(v, off, 32);
    if (o == 0) out[n] = v + fc2b[0];
}

extern "C" void kernel_launch(void* const* d_in, const int* in_sizes, int n_in,
                              void* d_out, int out_size, void* d_ws, size_t ws_size,
                              hipStream_t stream) {
    const float* x      = (const float*)d_in[0];
    const int*   ei     = (const int*)  d_in[1];
    const float* ea     = (const float*)d_in[2];
    const float* nn1_w1 = (const float*)d_in[3];
    const float* nn1_b1 = (const float*)d_in[4];
    const float* nn1_w2 = (const float*)d_in[5];
    const float* nn1_b2 = (const float*)d_in[6];
    const float* root1  = (const float*)d_in[7];
    const float* bias1  = (const float*)d_in[8];
    const float* nn2_w1 = (const float*)d_in[9];
    const float* nn2_b1 = (const float*)d_in[10];
    const float* nn2_w2 = (const float*)d_in[11];
    const float* nn2_b2 = (const float*)d_in[12];
    const float* root2  = (const float*)d_in[13];
    const float* bias2  = (const float*)d_in[14];
    const float* fc2w   = (const float*)d_in[15];
    const float* fc2b   = (const float*)d_in[16];

    const int N = in_sizes[0] / 2;
    const int E = in_sizes[2] / 2;

    float* agg1 = (float*)d_ws;
    float* agg2 = agg1 + (size_t)N * 32;
    float* h1   = agg2 + (size_t)N * 32;

    hipMemsetAsync(d_ws, 0, (size_t)N * 64 * sizeof(float), stream);

    edge1_mfma<<<1024, 256, 0, stream>>>(
        x, ei, ea, nn1_w1, nn1_b1, nn1_w2, nn1_b2, agg1, E);

    node1_kernel<<<(N * 32 + 255) / 256, 256, 0, stream>>>(
        x, agg1, root1, bias1, h1, N);

    edge2_mfma<<<1024, 256, 0, stream>>>(
        h1, ei, ea, nn2_w1, nn2_b1, nn2_w2, nn2_b2, agg2, E);

    node2_kernel<<<(N * 32 + 255) / 256, 256, 0, stream>>>(
        h1, agg2, root2, bias2, fc2w, fc2b, (float*)d_out, N);
}

// Round 7
// 168.502 us; speedup vs baseline: 2.0851x; 1.0083x over previous
//
#include <hip/hip_runtime.h>
#include <hip/hip_bf16.h>

// ---------------------------------------------------------------------------
// Net_MP: two NNConv layers (2->32, 32->32) + Linear(32->1) on a graph.
// Edge phases: per-edge outer-product u[e] (K = 16*IN + IN) contracted with a
// shared WrT[K,32] via bf16 MFMA; A-fragments built directly in registers.
// node1 is FUSED into edge2 and node2 (h1 recomputed on the fly from agg1),
// eliminating one dispatch and the h1 round-trip.
// ---------------------------------------------------------------------------

typedef __attribute__((ext_vector_type(8))) short short8;   // 8 bf16
typedef __attribute__((ext_vector_type(4))) float f32x4;

union frag_u { short8 s; unsigned u[4]; };

__device__ inline unsigned cvt_pk2(float lo, float hi) {
    union { __hip_bfloat162 h; unsigned u; } c;
    c.h = __float22bfloat162_rn(make_float2(lo, hi));   // v_cvt_pk_bf16_f32
    return c.u;
}
__device__ inline float relu(float v) { return v > 0.f ? v : 0.f; }

// ============ conv2 edge phase (K = 544), node1 fused in ===================
__global__ __launch_bounds__(256, 3) void edge2_fused(
    const float* __restrict__ x,     // [N,2]
    const float* __restrict__ agg1,  // [N,32] (conv1 aggregate, complete)
    const int*   __restrict__ ei,    // [2,E]
    const float* __restrict__ ea,    // [E,2]
    const float* __restrict__ root1, // [2,32]
    const float* __restrict__ bias1, // [32]
    const float* __restrict__ w1,    // nn2_w1 [2,16]
    const float* __restrict__ b1,    // nn2_b1 [16]
    const float* __restrict__ w2,    // nn2_w2 [16,1024] = [16][32in][32out]
    const float* __restrict__ b2,    // nn2_b2 [1024] = [32in][32out]
    float* __restrict__ agg,         // [N,32] atomic accum (agg2)
    int E)
{
    const int tid  = threadIdx.x;
    const int lane = tid & 63;
    const int wv   = tid >> 6;          // 0..3
    const int nh   = wv & 1;            // output half (16 cols)
    const int gsel = wv >> 1;           // edge-group within pair
    const int r16  = lane & 15;
    const int g    = lane >> 4;         // k-slice / D row-quad
    const int oo   = nh * 16 + r16;     // my output column
    const int g8   = g * 8;

    // ---- one-time: B fragments from global (w2 is L2-resident) ----
    short8 bfrag[17];
#pragma unroll
    for (int t = 0; t < 16; ++t) {
        frag_u f;
#pragma unroll
        for (int wd = 0; wd < 4; ++wd) {
            int i0 = g8 + 2 * wd;
            f.u[wd] = cvt_pk2(w2[t * 1024 + i0 * 32 + oo],
                              w2[t * 1024 + (i0 + 1) * 32 + oo]);
        }
        bfrag[t] = f.s;
    }
    {   // bias rows: kk = 512 + i  ->  b2[i*32 + oo]
        frag_u f;
#pragma unroll
        for (int wd = 0; wd < 4; ++wd) {
            int i0 = g8 + 2 * wd;
            f.u[wd] = cvt_pk2(b2[i0 * 32 + oo], b2[(i0 + 1) * 32 + oo]);
        }
        bfrag[16] = f.s;
    }

    // ---- node1 constants for my input slice j = g8..g8+7 ----
    const float4 r0a = *(const float4*)(root1 + g8);
    const float4 r0b = *(const float4*)(root1 + g8 + 4);
    const float4 r1a = *(const float4*)(root1 + 32 + g8);
    const float4 r1b = *(const float4*)(root1 + 32 + g8 + 4);
    const float4 b1a = *(const float4*)(bias1 + g8);
    const float4 b1b = *(const float4*)(bias1 + g8 + 4);

    // ---- edge-MLP weights (uniform) ----
    float w1r0[16], w1r1[16], b1r[16];
#pragma unroll
    for (int k = 0; k < 16; ++k) {
        w1r0[k] = w1[k]; w1r1[k] = w1[16 + k]; b1r[k] = b1[k];
    }

    const int pairs = (E + 31) >> 5;    // 32 edges per block-iter (2 groups)
    int p = blockIdx.x;
    if (p >= pairs) return;

    // prefetch level-1 loads for the first iteration
    int base_c = p * 32 + gsel * 16;
    int ec     = min(base_c + r16, E - 1);
    int    src_c = ei[ec];
    float2 ea_c  = *(const float2*)(ea + 2 * (size_t)ec);
    int4   d4_c  = *(const int4*)(ei + (size_t)E + min(base_c + g * 4, E - 4));

    for (; p < pairs; p += gridDim.x) {
        const int base = base_c;
        const bool ev  = (base + r16) < E;

        // dependent gathers for current iteration
        float2 xv = *(const float2*)(x + 2 * (size_t)src_c);
        float4 aA = *(const float4*)(agg1 + (size_t)src_c * 32 + g8);
        float4 aB = *(const float4*)(agg1 + (size_t)src_c * 32 + g8 + 4);
        float2 eav = ea_c;
        int4   d4  = d4_c;

        // prefetch level-1 loads for next iteration (independent)
        int pn = p + gridDim.x;
        if (pn < pairs) {
            base_c = pn * 32 + gsel * 16;
            int ecn = min(base_c + r16, E - 1);
            src_c = ei[ecn];
            ea_c  = *(const float2*)(ea + 2 * (size_t)ecn);
            d4_c  = *(const int4*)(ei + (size_t)E + min(base_c + g * 4, E - 4));
        }

        // ---- node1 fused: h1[src][g8..g8+7] ----
        float4 hA, hB;
        hA.x = relu(aA.x + xv.x * r0a.x + xv.y * r1a.x + b1a.x);
        hA.y = relu(aA.y + xv.x * r0a.y + xv.y * r1a.y + b1a.y);
        hA.z = relu(aA.z + xv.x * r0a.z + xv.y * r1a.z + b1a.z);
        hA.w = relu(aA.w + xv.x * r0a.w + xv.y * r1a.w + b1a.w);
        hB.x = relu(aB.x + xv.x * r0b.x + xv.y * r1b.x + b1b.x);
        hB.y = relu(aB.y + xv.x * r0b.y + xv.y * r1b.y + b1b.y);
        hB.z = relu(aB.z + xv.x * r0b.z + xv.y * r1b.z + b1b.z);
        hB.w = relu(aB.w + xv.x * r0b.w + xv.y * r1b.w + b1b.w);
        if (!ev) { hA = make_float4(0.f,0.f,0.f,0.f); hB = make_float4(0.f,0.f,0.f,0.f); }

        // ---- edge MLP: he[k] ----
        float he[16];
#pragma unroll
        for (int k = 0; k < 16; ++k)
            he[k] = relu(fmaf(eav.x, w1r0[k], fmaf(eav.y, w1r1[k], b1r[k])));

        // ---- MFMA chain over K = 544 ----
        f32x4 acc = {0.f, 0.f, 0.f, 0.f};
#pragma unroll
        for (int t = 0; t < 16; ++t) {
            frag_u a;
            a.u[0] = cvt_pk2(he[t] * hA.x, he[t] * hA.y);
            a.u[1] = cvt_pk2(he[t] * hA.z, he[t] * hA.w);
            a.u[2] = cvt_pk2(he[t] * hB.x, he[t] * hB.y);
            a.u[3] = cvt_pk2(he[t] * hB.z, he[t] * hB.w);
            acc = __builtin_amdgcn_mfma_f32_16x16x32_bf16(a.s, bfrag[t], acc, 0, 0, 0);
        }
        {   // bias rows: u[512+i] = hsrc[i]
            frag_u a;
            a.u[0] = cvt_pk2(hA.x, hA.y);
            a.u[1] = cvt_pk2(hA.z, hA.w);
            a.u[2] = cvt_pk2(hB.x, hB.y);
            a.u[3] = cvt_pk2(hB.z, hB.w);
            acc = __builtin_amdgcn_mfma_f32_16x16x32_bf16(a.s, bfrag[16], acc, 0, 0, 0);
        }

        // ---- scatter: D row r = g*4+j -> edge base+g*4+j, col = oo ----
        float* ap = agg + oo;
        if (base + g * 4 + 3 < E) {
            atomicAdd(ap + (size_t)d4.x * 32, acc[0]);
            atomicAdd(ap + (size_t)d4.y * 32, acc[1]);
            atomicAdd(ap + (size_t)d4.z * 32, acc[2]);
            atomicAdd(ap + (size_t)d4.w * 32, acc[3]);
        } else {
#pragma unroll
            for (int j = 0; j < 4; ++j) {
                int eg = base + g * 4 + j;
                if (eg < E) atomicAdd(ap + (size_t)ei[E + eg] * 32, acc[j]);
            }
        }
    }
}

// ======================= conv1 edge phase (K = 64) =========================
__global__ __launch_bounds__(256, 4) void edge1_mfma(
    const float* __restrict__ x,    // [N,2]
    const int*   __restrict__ ei,
    const float* __restrict__ ea,
    const float* __restrict__ w1,   // [2,16]
    const float* __restrict__ b1,   // [16]
    const float* __restrict__ w2,   // [16,64] = [16][2][32]
    const float* __restrict__ b2,   // [64] = [2][32]
    float* __restrict__ agg,        // [N,32]
    int E)
{
    const int tid  = threadIdx.x;
    const int lane = tid & 63;
    const int wv   = tid >> 6;
    const int nh   = wv & 1;
    const int gsel = wv >> 1;
    const int r16  = lane & 15;
    const int g    = lane >> 4;
    const int oo   = nh * 16 + r16;
    const int g8   = g * 8;

    // B fragments
    short8 bf0, bf1;
    {
        frag_u f;
#pragma unroll
        for (int wd = 0; wd < 4; ++wd) {
            int kk0 = g8 + 2 * wd, kk1 = kk0 + 1;
            f.u[wd] = cvt_pk2(w2[(kk0 >> 1) * 64 + (kk0 & 1) * 32 + oo],
                              w2[(kk1 >> 1) * 64 + (kk1 & 1) * 32 + oo]);
        }
        bf0 = f.s;
        f.u[0] = (g == 0) ? cvt_pk2(b2[oo], b2[32 + oo]) : 0u;
        f.u[1] = 0u; f.u[2] = 0u; f.u[3] = 0u;
        bf1 = f.s;
    }

    const float4 w1a = *(const float4*)(w1 + g * 4);        // w1[0][g4..]
    const float4 w1b = *(const float4*)(w1 + 16 + g * 4);   // w1[1][g4..]
    const float4 b1v = *(const float4*)(b1 + g * 4);

    const int pairs = (E + 31) >> 5;
    for (int p = blockIdx.x; p < pairs; p += gridDim.x) {
        const int base = p * 32 + gsel * 16;
        const int edge = base + r16;
        const bool ev = edge < E;
        const int ec = ev ? edge : 0;

        int    src = ei[ec];
        float2 eav = *(const float2*)(ea + 2 * (size_t)ec);
        float2 xv  = *(const float2*)(x + 2 * (size_t)src);
        if (!ev) xv = make_float2(0.f, 0.f);

        float he0 = relu(fmaf(eav.x, w1a.x, fmaf(eav.y, w1b.x, b1v.x)));
        float he1 = relu(fmaf(eav.x, w1a.y, fmaf(eav.y, w1b.y, b1v.y)));
        float he2 = relu(fmaf(eav.x, w1a.z, fmaf(eav.y, w1b.z, b1v.z)));
        float he3 = relu(fmaf(eav.x, w1a.w, fmaf(eav.y, w1b.w, b1v.w)));

        frag_u a;
        a.u[0] = cvt_pk2(he0 * xv.x, he0 * xv.y);
        a.u[1] = cvt_pk2(he1 * xv.x, he1 * xv.y);
        a.u[2] = cvt_pk2(he2 * xv.x, he2 * xv.y);
        a.u[3] = cvt_pk2(he3 * xv.x, he3 * xv.y);
        f32x4 acc = {0.f, 0.f, 0.f, 0.f};
        acc = __builtin_amdgcn_mfma_f32_16x16x32_bf16(a.s, bf0, acc, 0, 0, 0);

        a.u[0] = (g == 0) ? cvt_pk2(xv.x, xv.y) : 0u;
        a.u[1] = 0u; a.u[2] = 0u; a.u[3] = 0u;
        acc = __builtin_amdgcn_mfma_f32_16x16x32_bf16(a.s, bf1, acc, 0, 0, 0);

        float* ap = agg + oo;
        if (base + g * 4 + 3 < E) {
            int4 d4 = *(const int4*)(ei + (size_t)E + base + g * 4);
            atomicAdd(ap + (size_t)d4.x * 32, acc[0]);
            atomicAdd(ap + (size_t)d4.y * 32, acc[1]);
            atomicAdd(ap + (size_t)d4.z * 32, acc[2]);
            atomicAdd(ap + (size_t)d4.w * 32, acc[3]);
        } else {
#pragma unroll
            for (int j = 0; j < 4; ++j) {
                int eg = base + g * 4 + j;
                if (eg < E) atomicAdd(ap + (size_t)ei[E + eg] * 32, acc[j]);
            }
        }
    }
}

// ---- node2 + fc2 (node1 fused): out = relu(agg2 + h1@root2 + b2)@fc2 + b --
__global__ __launch_bounds__(256) void node2_fused(
    const float* __restrict__ x,     // [N,2]
    const float* __restrict__ agg1,  // [N,32]
    const float* __restrict__ agg2,  // [N,32]
    const float* __restrict__ root1, // [2,32]
    const float* __restrict__ bias1, // [32]
    const float* __restrict__ root2, // [32,32]
    const float* __restrict__ bias2, // [32]
    const float* __restrict__ fc2w,  // [32,1]
    const float* __restrict__ fc2b,  // [1]
    float* __restrict__ out,         // [N]
    int N)
{
    __shared__ float s_r[1024];
    for (int t = threadIdx.x; t < 1024; t += blockDim.x) s_r[t] = root2[t];
    __syncthreads();

    int gid = blockIdx.x * blockDim.x + threadIdx.x;
    int n = gid >> 5, o = gid & 31;
    if (n >= N) return;

    float2 xv = *(const float2*)(x + 2 * (size_t)n);
    float h1o = relu(agg1[(size_t)n * 32 + o]
                   + xv.x * root1[o] + xv.y * root1[32 + o] + bias1[o]);

    float v = agg2[(size_t)n * 32 + o] + bias2[o];
#pragma unroll
    for (int i = 0; i < 32; ++i) {
        float hi = __shfl(h1o, i, 32);
        v = fmaf(hi, s_r[i * 32 + o], v);
    }
    v = relu(v);
    v *= fc2w[o];
#pragma unroll
    for (int off = 16; off; off >>= 1) v += __shfl_xor(v, off, 32);
    if (o == 0) out[n] = v + fc2b[0];
}

extern "C" void kernel_launch(void* const* d_in, const int* in_sizes, int n_in,
                              void* d_out, int out_size, void* d_ws, size_t ws_size,
                              hipStream_t stream) {
    const float* x      = (const float*)d_in[0];
    const int*   ei     = (const int*)  d_in[1];
    const float* ea     = (const float*)d_in[2];
    const float* nn1_w1 = (const float*)d_in[3];
    const float* nn1_b1 = (const float*)d_in[4];
    const float* nn1_w2 = (const float*)d_in[5];
    const float* nn1_b2 = (const float*)d_in[6];
    const float* root1  = (const float*)d_in[7];
    const float* bias1  = (const float*)d_in[8];
    const float* nn2_w1 = (const float*)d_in[9];
    const float* nn2_b1 = (const float*)d_in[10];
    const float* nn2_w2 = (const float*)d_in[11];
    const float* nn2_b2 = (const float*)d_in[12];
    const float* root2  = (const float*)d_in[13];
    const float* bias2  = (const float*)d_in[14];
    const float* fc2w   = (const float*)d_in[15];
    const float* fc2b   = (const float*)d_in[16];

    const int N = in_sizes[0] / 2;
    const int E = in_sizes[2] / 2;

    float* agg1 = (float*)d_ws;                  // [N,32]
    float* agg2 = agg1 + (size_t)N * 32;         // [N,32]

    hipMemsetAsync(d_ws, 0, (size_t)N * 64 * sizeof(float), stream);

    edge1_mfma<<<1024, 256, 0, stream>>>(
        x, ei, ea, nn1_w1, nn1_b1, nn1_w2, nn1_b2, agg1, E);

    edge2_fused<<<768, 256, 0, stream>>>(
        x, agg1, ei, ea, root1, bias1,
        nn2_w1, nn2_b1, nn2_w2, nn2_b2, agg2, E);

    node2_fused<<<(N * 32 + 255) / 256, 256, 0, stream>>>(
        x, agg1, agg2, root1, bias1, root2, bias2, fc2w, fc2b,
        (float*)d_out, N);
}